// Round 1
// 282.577 us; speedup vs baseline: 1.0078x; 1.0078x over previous
//
#include <hip/hip_runtime.h>
#include <hip/hip_bf16.h>

// GCN 2-layer forward on MI355X.
// Round-10 changes (agg kernels issue/dependency bound: ~27 wave-slots/edge
// measured vs ~2 irreducible; the ds_bpermute broadcast + take/mask
// machinery and its lgkm->vmem serial chain dominated):
//  - Direct per-group col loads (16 lanes share one address -> coalesced
//    broadcast) replace idx staging + dynamic __shfl. Pad lanes use a
//    v_cndmask to sentinel row n; col gets 64 ints of slack so the
//    unconditional load is in-bounds.
//  - row_ptr/count forced to SGPR via readfirstlane -> scalar loop control.
//  - Packed f32 accumulation (float2v += cvt_pk result -> v_pk_add_f32).
//  - __expf/__logf in the softmax tail (error << fp8 quantization floor).
// Pre-scaled fp8 features (r9), CSR build (r5), MFMA GEMMs (r4) kept.

typedef unsigned short ushortT;
typedef unsigned char ucharT;
typedef __attribute__((ext_vector_type(8))) short short8v;        // 8 bf16 (4 VGPR)
typedef __attribute__((ext_vector_type(4))) float float4v;        // MFMA C/D
typedef __attribute__((ext_vector_type(2))) float float2v;
typedef __attribute__((ext_vector_type(8))) unsigned short ushort8v;

__device__ __forceinline__ float bf2f(ushortT u) {
  union { unsigned int i; float f; } x;
  x.i = ((unsigned int)u) << 16;
  return x.f;
}

__device__ __forceinline__ ushortT f2bf(float f) {
  __hip_bfloat16 h = __float2bfloat16(f);  // RNE
  return *(ushortT*)&h;
}

__device__ __forceinline__ ucharT f2fp8(float f) {
  unsigned int w = __builtin_amdgcn_cvt_pk_fp8_f32(f, f, 0, false);
  return (ucharT)(w & 0xff);
}

// decode 8 fp8 bytes (two dwords) into f[0..7]
__device__ __forceinline__ void fp8x8_to_f32(unsigned int lo, unsigned int hi,
                                             float* f) {
  float2v p0 = __builtin_amdgcn_cvt_pk_f32_fp8(lo, false);  // bytes 0,1
  float2v p1 = __builtin_amdgcn_cvt_pk_f32_fp8(lo, true);   // bytes 2,3
  float2v p2 = __builtin_amdgcn_cvt_pk_f32_fp8(hi, false);
  float2v p3 = __builtin_amdgcn_cvt_pk_f32_fp8(hi, true);
  f[0] = p0[0]; f[1] = p0[1]; f[2] = p1[0]; f[3] = p1[1];
  f[4] = p2[0]; f[5] = p2[1]; f[6] = p3[0]; f[7] = p3[1];
}

// decode 4 fp8 bytes (one dword) into f[0..3]
__device__ __forceinline__ void fp8x4_to_f32(unsigned int w, float* f) {
  float2v p0 = __builtin_amdgcn_cvt_pk_f32_fp8(w, false);
  float2v p1 = __builtin_amdgcn_cvt_pk_f32_fp8(w, true);
  f[0] = p0[0]; f[1] = p0[1]; f[2] = p1[0]; f[3] = p1[1];
}

// ---------------- dtype probe ----------------
__global__ void probe_k(const ushortT* __restrict__ xr, int* __restrict__ flag) {
  const int lane = threadIdx.x;  // 64 threads
  float v = bf2f(xr[lane]);
  bool sane = isfinite(v) && fabsf(v) < 1e4f;
  unsigned long long m = __ballot(sane);
  if (lane == 0) flag[0] = (m == ~0ull) ? 1 : 0;
}

// ---------------- W transpose prep: Wt1[nn][k] (128x128), Wt2[nn][k] (64x128) ----------------
__global__ __launch_bounds__(256) void wprep_k(const void* __restrict__ W1v,
                                               const void* __restrict__ W2v,
                                               const int* __restrict__ flag,
                                               ushortT* __restrict__ Wt1,
                                               ushortT* __restrict__ Wt2) {
  const int i = blockIdx.x * 256 + threadIdx.x;  // 0..24575
  const bool isbf = (flag[0] != 0);
  if (i < 16384) {
    int nn = i & 127, k = i >> 7;   // read W1[k][nn] coalesced in nn
    ushortT v = isbf ? ((const ushortT*)W1v)[k * 128 + nn]
                     : f2bf(((const float*)W1v)[k * 128 + nn]);
    Wt1[nn * 128 + k] = v;
  } else if (i < 24576) {
    int j = i - 16384;
    int nn = j & 63, k = j >> 6;    // read W2[k][nn] coalesced in nn
    ushortT v = isbf ? ((const ushortT*)W2v)[k * 64 + nn]
                     : f2bf(((const float*)W2v)[k * 64 + nn]);
    Wt2[nn * 128 + k] = v;
  }
}

// ---------------- bucketed CSR build ----------------
// bucket b = dst >> 8 (256 nodes/bucket), B = ceil(n/256)

__global__ __launch_bounds__(256) void bhist_k(const int* __restrict__ dst, int E, int B,
                                               int* __restrict__ gbc) {
  __shared__ int h[512];
  const int tid = threadIdx.x;
  for (int i = tid; i < B; i += 256) h[i] = 0;
  __syncthreads();
  const int i0 = blockIdx.x * 8192;
  const int iend = min(i0 + 8192, E);
  for (int i = i0 + tid; i < iend; i += 256) atomicAdd(&h[dst[i] >> 8], 1);
  __syncthreads();
  for (int i = tid; i < B; i += 256)
    if (h[i]) atomicAdd(&gbc[i], h[i]);
}

__global__ __launch_bounds__(256) void bscan_k(const int* __restrict__ gbc, int B,
                                               int* __restrict__ bbase,
                                               int* __restrict__ gcur) {
  __shared__ int p[256];
  const int t = threadIdx.x;
  int a = (2 * t < B) ? gbc[2 * t] : 0;
  int b = (2 * t + 1 < B) ? gbc[2 * t + 1] : 0;
  const int sum = a + b;
  p[t] = sum;
  __syncthreads();
  int run = sum;
  for (int off = 1; off < 256; off <<= 1) {
    int v = (t >= off) ? p[t - off] : 0;
    __syncthreads();
    run += v;
    p[t] = run;
    __syncthreads();
  }
  const int excl = run - sum;
  if (2 * t < B) { bbase[2 * t] = excl; gcur[2 * t] = excl; }
  if (2 * t + 1 < B) { bbase[2 * t + 1] = excl + a; gcur[2 * t + 1] = excl + a; }
}

__global__ __launch_bounds__(256) void bin_k(const int* __restrict__ srcv,
                                             const int* __restrict__ dstv, int E, int B,
                                             int* __restrict__ gcur,
                                             int* __restrict__ tmp) {
  __shared__ int hist[512];
  __shared__ int base[512];
  const int tid = threadIdx.x;
  const int i0 = blockIdx.x * 8192;
  const int iend = min(i0 + 8192, E);
  for (int i = tid; i < B; i += 256) hist[i] = 0;
  __syncthreads();
  for (int i = i0 + tid; i < iend; i += 256) atomicAdd(&hist[dstv[i] >> 8], 1);
  __syncthreads();
  for (int i = tid; i < B; i += 256) {
    int h = hist[i];
    base[i] = h ? atomicAdd(&gcur[i], h) : 0;
    hist[i] = 0;  // reuse as local cursor
  }
  __syncthreads();
  for (int i = i0 + tid; i < iend; i += 256) {
    int d = dstv[i];
    int s = srcv[i];
    int b = d >> 8;
    int l = atomicAdd(&hist[b], 1);
    tmp[base[b] + l] = s | ((d & 255) << 17);  // n < 2^17 required (n=100k)
  }
}

// wg per bucket: per-node counts, row_ptr, dis, final in-bucket scatter
__global__ __launch_bounds__(256) void csr_k(const int* __restrict__ tmp,
                                             const int* __restrict__ bbase,
                                             const int* __restrict__ gbc, int n,
                                             int* __restrict__ row_ptr,
                                             int* __restrict__ cnt,
                                             float* __restrict__ dis,
                                             int* __restrict__ col) {
  __shared__ int lhist[256];
  __shared__ int lexcl[256];
  const int b = blockIdx.x;
  const int tid = threadIdx.x;
  const int e0 = bbase[b];
  const int e1 = e0 + gbc[b];
  lhist[tid] = 0;
  __syncthreads();
  for (int i = e0 + tid; i < e1; i += 256) atomicAdd(&lhist[tmp[i] >> 17], 1);
  __syncthreads();
  const int v = lhist[tid];
  int run = v;
  lexcl[tid] = run;
  __syncthreads();
  for (int off = 1; off < 256; off <<= 1) {
    int t = (tid >= off) ? lexcl[tid - off] : 0;
    __syncthreads();
    run += t;
    lexcl[tid] = run;
    __syncthreads();
  }
  const int excl = run - v;
  const int node = (b << 8) + tid;
  if (node < n) {
    row_ptr[node] = e0 + excl;
    cnt[node] = v;
    dis[node] = rsqrtf((float)(v + 1));
  }
  lhist[tid] = 0;
  lexcl[tid] = excl;
  __syncthreads();
  for (int i = e0 + tid; i < e1; i += 256) {
    int p = tmp[i];
    int dloc = p >> 17;
    int s = p & 131071;
    int l = atomicAdd(&lhist[dloc], 1);
    col[e0 + lexcl[dloc] + l] = s;
  }
}

// ---------------- GEMM1 (MFMA): H1'[n+1,128](fp8) = dis * (x @ W1) ----------------
__global__ __launch_bounds__(256) void gemm1_k(const void* __restrict__ xv,
                                               const ushortT* __restrict__ Wt1,
                                               const float* __restrict__ dis,
                                               const int* __restrict__ flag,
                                               ucharT* __restrict__ Hb8, int n) {
  __shared__ ushortT sA[64 * 132];
  __shared__ ushortT sW[128 * 132];
  const bool isbf = (flag[0] != 0);
  const int tid = threadIdx.x;
  const int rb = blockIdx.x * 64;
  const int wave = tid >> 6;
  const int lane = tid & 63;
  const int m = lane & 15;
  const int quad = lane >> 4;

  if (isbf) {
    for (int i = tid; i < 2048; i += 256) {
      int r = i >> 5, c4 = (i & 31) * 4;
      ushort4 u = make_ushort4(0, 0, 0, 0);
      if (rb + r < n) u = *(const ushort4*)((const ushortT*)xv + (size_t)(rb + r) * 128 + c4);
      *(ushort4*)&sA[r * 132 + c4] = u;
    }
  } else {
    for (int i = tid; i < 2048; i += 256) {
      int r = i >> 5, c4 = (i & 31) * 4;
      float4 v = make_float4(0.f, 0.f, 0.f, 0.f);
      if (rb + r < n) v = *(const float4*)((const float*)xv + (size_t)(rb + r) * 128 + c4);
      ushort4 u;
      u.x = f2bf(v.x); u.y = f2bf(v.y); u.z = f2bf(v.z); u.w = f2bf(v.w);
      *(ushort4*)&sA[r * 132 + c4] = u;
    }
  }
  // stage Wt1 (coalesced 16B): 128 rows x 128 k = 4096 ushort4 chunks
  for (int i = tid; i < 4096; i += 256) {
    int nn = i >> 5, k4 = (i & 31) * 4;
    *(ushort4*)&sW[nn * 132 + k4] = *(const ushort4*)&Wt1[nn * 128 + k4];
  }
  __syncthreads();

  float4v acc[8];
#pragma unroll
  for (int t = 0; t < 8; ++t) acc[t] = (float4v)(0.f);

  const int arow = wave * 16 + m;
#pragma unroll
  for (int kc = 0; kc < 4; ++kc) {
    short8v af = *(const short8v*)&sA[arow * 132 + kc * 32 + quad * 8];
#pragma unroll
    for (int nb = 0; nb < 8; ++nb) {
      short8v bf = *(const short8v*)&sW[(nb * 16 + m) * 132 + kc * 32 + quad * 8];
      acc[nb] = __builtin_amdgcn_mfma_f32_16x16x32_bf16(af, bf, acc[nb], 0, 0, 0);
    }
  }

  // D: row = rb + wave*16 + quad*4 + r, col = nb*16 + m; store dis*val fp8
  // row n (sentinel) gets zeros. acc==0 for rows >= n (zero-staged x).
#pragma unroll
  for (int r = 0; r < 4; ++r) {
    int grow = rb + wave * 16 + quad * 4 + r;
    if (grow <= n) {
      float sc = (grow < n) ? dis[grow] : 0.f;
#pragma unroll
      for (int nb = 0; nb < 8; ++nb)
        Hb8[(size_t)grow * 128 + nb * 16 + m] =
            (grow < n) ? f2fp8(sc * acc[nb][r]) : (ucharT)0;
    }
  }
}

// ---------------- agg1: A = relu(din*(sum H1'[s] + H1'[i]) + b1) ----------------
// wave per node; four 16-lane quarters, one edge per quarter per step,
// 8 channels/lane (8B fp8 load). col loaded directly per group (broadcast
// address); pad lanes cndmask to sentinel row n (zeros). Packed f32 accum.
__global__ __launch_bounds__(256) void agg1_k(const ucharT* __restrict__ Hb8,
                                              const int* __restrict__ col,
                                              const int* __restrict__ row_ptr,
                                              const int* __restrict__ count,
                                              const float* __restrict__ dis,
                                              const void* __restrict__ b1v,
                                              const int* __restrict__ flag,
                                              ushortT* __restrict__ Ab, int n) {
  const int node = blockIdx.x * 4 + (threadIdx.x >> 6);
  if (node >= n) return;
  const bool isbf = (flag[0] != 0);
  const int lane = threadIdx.x & 63;
  const int quad = lane >> 4;       // edge slot within a 4-group
  const int c8 = (lane & 15) * 8;   // 8-channel slice (1B/ch)
  const int start = __builtin_amdgcn_readfirstlane(row_ptr[node]);
  const int cnt = __builtin_amdgcn_readfirstlane(count[node]);

  float2v acc[4];
#pragma unroll
  for (int k = 0; k < 4; ++k) acc[k] = (float2v)(0.f);

  for (int e0 = 0; e0 < cnt; e0 += 16) {
#pragma unroll
    for (int g = 0; g < 4; ++g) {
      const int e = e0 + g * 4 + quad;
      int s = col[start + e];          // col has 64 ints slack; garbage ok
      s = (e < cnt) ? s : n;           // sentinel: zero row
      uint2 h = *(const uint2*)&Hb8[((unsigned)s << 7) + (unsigned)c8];
      acc[0] += __builtin_amdgcn_cvt_pk_f32_fp8(h.x, false);
      acc[1] += __builtin_amdgcn_cvt_pk_f32_fp8(h.x, true);
      acc[2] += __builtin_amdgcn_cvt_pk_f32_fp8(h.y, false);
      acc[3] += __builtin_amdgcn_cvt_pk_f32_fp8(h.y, true);
    }
  }

  // merge quarters
  float accs[8];
#pragma unroll
  for (int k = 0; k < 4; ++k) { accs[2 * k] = acc[k][0]; accs[2 * k + 1] = acc[k][1]; }
#pragma unroll
  for (int k = 0; k < 8; ++k) {
    accs[k] += __shfl_xor(accs[k], 16);
    accs[k] += __shfl_xor(accs[k], 32);
  }

  const float din = dis[node];
  uint2 hsp = *(const uint2*)&Hb8[((unsigned)node << 7) + (unsigned)c8];
  float hs[8];
  fp8x8_to_f32(hsp.x, hsp.y, hs);
  float b[8];
  if (isbf) {
    ushort8v bb = *(const ushort8v*)((const ushortT*)b1v + c8);
#pragma unroll
    for (int k = 0; k < 8; ++k) b[k] = bf2f(bb[k]);
  } else {
    const float* bf = (const float*)b1v + c8;
#pragma unroll
    for (int k = 0; k < 8; ++k) b[k] = bf[k];
  }
  if (quad == 0) {
    ushort8v o;
#pragma unroll
    for (int k = 0; k < 8; ++k)
      o[k] = f2bf(fmaxf(fmaf(din, accs[k] + hs[k], b[k]), 0.f));
    *(ushort8v*)&Ab[(size_t)node * 128 + c8] = o;
  }
}

// ---------------- GEMM2 (MFMA): H2'[n+1,64](fp8) = dis * (A @ W2) ----------------
__global__ __launch_bounds__(256) void gemm2_k(const ushortT* __restrict__ Ab,
                                               const ushortT* __restrict__ Wt2,
                                               const float* __restrict__ dis,
                                               ucharT* __restrict__ H2b8, int n) {
  __shared__ ushortT sA[64 * 132];
  __shared__ ushortT sW[64 * 132];
  const int tid = threadIdx.x;
  const int rb = blockIdx.x * 64;
  const int wave = tid >> 6;
  const int lane = tid & 63;
  const int m = lane & 15;
  const int quad = lane >> 4;

  for (int i = tid; i < 2048; i += 256) {
    int r = i >> 5, c4 = (i & 31) * 4;
    ushort4 u = make_ushort4(0, 0, 0, 0);
    if (rb + r < n) u = *(const ushort4*)&Ab[(size_t)(rb + r) * 128 + c4];
    *(ushort4*)&sA[r * 132 + c4] = u;
  }
  // stage Wt2 (coalesced 16B): 64 rows x 128 k = 2048 ushort4 chunks
  for (int i = tid; i < 2048; i += 256) {
    int nn = i >> 5, k4 = (i & 31) * 4;
    *(ushort4*)&sW[nn * 132 + k4] = *(const ushort4*)&Wt2[nn * 128 + k4];
  }
  __syncthreads();

  float4v acc[4];
#pragma unroll
  for (int t = 0; t < 4; ++t) acc[t] = (float4v)(0.f);

  const int arow = wave * 16 + m;
#pragma unroll
  for (int kc = 0; kc < 4; ++kc) {
    short8v af = *(const short8v*)&sA[arow * 132 + kc * 32 + quad * 8];
#pragma unroll
    for (int nb = 0; nb < 4; ++nb) {
      short8v bf = *(const short8v*)&sW[(nb * 16 + m) * 132 + kc * 32 + quad * 8];
      acc[nb] = __builtin_amdgcn_mfma_f32_16x16x32_bf16(af, bf, acc[nb], 0, 0, 0);
    }
  }

#pragma unroll
  for (int r = 0; r < 4; ++r) {
    int grow = rb + wave * 16 + quad * 4 + r;
    if (grow <= n) {
      float sc = (grow < n) ? dis[grow] : 0.f;
#pragma unroll
      for (int nb = 0; nb < 4; ++nb)
        H2b8[(size_t)grow * 64 + nb * 16 + m] =
            (grow < n) ? f2fp8(sc * acc[nb][r]) : (ucharT)0;
    }
  }
}

// ---------------- agg2 + log_softmax -> out ----------------
// wave per node; quarters, one edge per quarter per step, 4 ch/lane (4B
// fp8 load). Direct col loads + cndmask sentinel; packed f32 accum;
// softmax: local 4 + shfl_xor(1..8) over 16-lane group, __expf/__logf.
__global__ __launch_bounds__(256) void agg2_k(const ucharT* __restrict__ H2b8,
                                              const int* __restrict__ col,
                                              const int* __restrict__ row_ptr,
                                              const int* __restrict__ count,
                                              const float* __restrict__ dis,
                                              const void* __restrict__ b2v,
                                              const int* __restrict__ flag,
                                              void* __restrict__ outv, int n) {
  const int node = blockIdx.x * 4 + (threadIdx.x >> 6);
  if (node >= n) return;
  const bool isbf = (flag[0] != 0);
  const int lane = threadIdx.x & 63;
  const int quad = lane >> 4;
  const int c4 = (lane & 15) * 4;
  const int start = __builtin_amdgcn_readfirstlane(row_ptr[node]);
  const int cnt = __builtin_amdgcn_readfirstlane(count[node]);

  float2v acc[2];
  acc[0] = (float2v)(0.f);
  acc[1] = (float2v)(0.f);

  for (int e0 = 0; e0 < cnt; e0 += 16) {
#pragma unroll
    for (int g = 0; g < 4; ++g) {
      const int e = e0 + g * 4 + quad;
      int s = col[start + e];          // col has 64 ints slack; garbage ok
      s = (e < cnt) ? s : n;           // sentinel: zero row
      unsigned int h = *(const unsigned int*)&H2b8[((unsigned)s << 6) + (unsigned)c4];
      acc[0] += __builtin_amdgcn_cvt_pk_f32_fp8(h, false);
      acc[1] += __builtin_amdgcn_cvt_pk_f32_fp8(h, true);
    }
  }

  float av[4] = {acc[0][0], acc[0][1], acc[1][0], acc[1][1]};
#pragma unroll
  for (int k = 0; k < 4; ++k) {
    av[k] += __shfl_xor(av[k], 16);
    av[k] += __shfl_xor(av[k], 32);
  }

  const float din = dis[node];
  unsigned int hsp = *(const unsigned int*)&H2b8[((unsigned)node << 6) + (unsigned)c4];
  float hs[4];
  fp8x4_to_f32(hsp, hs);
  float b[4];
  if (isbf) {
    ushort4 bb = *(const ushort4*)((const ushortT*)b2v + c4);
    b[0] = bf2f(bb.x); b[1] = bf2f(bb.y); b[2] = bf2f(bb.z); b[3] = bf2f(bb.w);
  } else {
    const float* bf = (const float*)b2v + c4;
#pragma unroll
    for (int k = 0; k < 4; ++k) b[k] = bf[k];
  }
  float v[4];
#pragma unroll
  for (int k = 0; k < 4; ++k) v[k] = fmaf(din, av[k] + hs[k], b[k]);

  // log_softmax over 64 channels: local 4 + 16-lane group reduce
  float mx = fmaxf(fmaxf(v[0], v[1]), fmaxf(v[2], v[3]));
  for (int off = 1; off < 16; off <<= 1) mx = fmaxf(mx, __shfl_xor(mx, off));
  float ssum = __expf(v[0] - mx) + __expf(v[1] - mx) + __expf(v[2] - mx) + __expf(v[3] - mx);
  for (int off = 1; off < 16; off <<= 1) ssum += __shfl_xor(ssum, off);
  const float lse = mx + __logf(ssum);

  if (quad == 0) {
    if (isbf) {
      ushort4 o;
      o.x = f2bf(v[0] - lse); o.y = f2bf(v[1] - lse);
      o.z = f2bf(v[2] - lse); o.w = f2bf(v[3] - lse);
      *(ushort4*)((__hip_bfloat16*)outv + (size_t)node * 64 + c4) = o;
    } else {
      float4 o = make_float4(v[0] - lse, v[1] - lse, v[2] - lse, v[3] - lse);
      *(float4*)((float*)outv + (size_t)node * 64 + c4) = o;
    }
  }
}

// ---------------- launch ----------------

extern "C" void kernel_launch(void* const* d_in, const int* in_sizes, int n_in,
                              void* d_out, int out_size, void* d_ws, size_t ws_size,
                              hipStream_t stream) {
  const void* x  = d_in[0];
  const int*  ei = (const int*)d_in[1];
  const void* W1 = d_in[2];
  const void* b1 = d_in[3];
  const void* W2 = d_in[4];
  const void* b2 = d_in[5];

  const int n = in_sizes[0] / 128;
  const int E = in_sizes[1] / 2;
  const int B = (n + 255) >> 8;  // buckets of 256 nodes
  const int* srcv = ei;      // edge_index[0]
  const int* dstv = ei + E;  // edge_index[1]

  // workspace layout (~60 MB), 256B-aligned sections
  char* p = (char*)d_ws;
  auto alloc = [&](size_t bytes) {
    char* q = p;
    p += (bytes + 255) & ~(size_t)255;
    return q;
  };
  ucharT* Hb8 = (ucharT*)alloc((size_t)(n + 1) * 128);      // H1' fp8, +sentinel row
  ucharT* H2b8 = (ucharT*)alloc((size_t)(n + 1) * 64);      // H2' fp8, +sentinel row
  ushortT* Ab = (ushortT*)alloc((size_t)n * 128 * 2);       // A bf16
  float* dis = (float*)alloc((size_t)n * 4);
  int* cntA = (int*)alloc((size_t)n * 4);
  int* row_ptr = (int*)alloc((size_t)n * 4);
  int* gbc = (int*)alloc(512 * 4);
  int* bbase = (int*)alloc(512 * 4);
  int* gcur = (int*)alloc(512 * 4);
  int* flag = (int*)alloc(64 * 4);
  ushortT* Wt1 = (ushortT*)alloc(16384 * 2);
  ushortT* Wt2 = (ushortT*)alloc(8192 * 2);
  int* tmp = (int*)alloc((size_t)E * 4);
  int* col = (int*)alloc(((size_t)E + 64) * 4);  // +64 slack for pad-lane reads

  (void)hipMemsetAsync(gbc, 0, 512 * sizeof(int), stream);

  const int gChunks = (E + 8191) / 8192;

  probe_k<<<1, 64, 0, stream>>>((const ushortT*)x, flag);
  wprep_k<<<96, 256, 0, stream>>>(W1, W2, flag, Wt1, Wt2);
  bhist_k<<<gChunks, 256, 0, stream>>>(dstv, E, B, gbc);
  bscan_k<<<1, 256, 0, stream>>>(gbc, B, bbase, gcur);
  bin_k<<<gChunks, 256, 0, stream>>>(srcv, dstv, E, B, gcur, tmp);
  csr_k<<<B, 256, 0, stream>>>(tmp, bbase, gbc, n, row_ptr, cntA, dis, col);

  gemm1_k<<<(n + 63) / 64, 256, 0, stream>>>(x, Wt1, dis, flag, Hb8, n);
  agg1_k<<<(n + 3) / 4, 256, 0, stream>>>(Hb8, col, row_ptr, cntA, dis, b1, flag, Ab, n);
  gemm2_k<<<(n + 63) / 64, 256, 0, stream>>>(Ab, Wt2, dis, H2b8, n);
  agg2_k<<<(n + 3) / 4, 256, 0, stream>>>(H2b8, col, row_ptr, cntA, dis, b2, flag, d_out, n);
}

// Round 2
// 256.829 us; speedup vs baseline: 1.1089x; 1.1002x over previous
//
#include <hip/hip_runtime.h>
#include <hip/hip_bf16.h>

// GCN 2-layer forward on MI355X.
// Round-11 changes (agg1 still 46us: 24us pure VALU issue ~= 300 wave-instr
// per node; epilogue as expensive as edge loop because a wave co-owns one
// node and merges quads via shfl):
//  - quad-owns-node aggregation: each 16-lane quarter owns its own node
//    (4 nodes/wave, 16/block). No inter-quad reduce; epilogue runs 4 nodes
//    per wave with all 64 lanes active (~4x fewer epilogue instrs/node);
//    pad-to-wave-max-degree waste ~20% vs ~31%.
//  - (row_ptr,count) packed into one int2 gather (rpc).
//  - self-row + bias loads hoisted above the edge loop (latency hidden).
//  - probe_k dispatch removed: consumers compute the wave-uniform bf16
//    probe inline from x's first 64 halfwords (one hot cache line).
// Direct col loads + sentinel cndmask (r10), pre-scaled fp8 features (r9),
// bucketed CSR (r5), MFMA GEMMs (r4) kept.

typedef unsigned short ushortT;
typedef unsigned char ucharT;
typedef __attribute__((ext_vector_type(8))) short short8v;        // 8 bf16 (4 VGPR)
typedef __attribute__((ext_vector_type(4))) float float4v;        // MFMA C/D
typedef __attribute__((ext_vector_type(2))) float float2v;
typedef __attribute__((ext_vector_type(8))) unsigned short ushort8v;

__device__ __forceinline__ float bf2f(ushortT u) {
  union { unsigned int i; float f; } x;
  x.i = ((unsigned int)u) << 16;
  return x.f;
}

__device__ __forceinline__ ushortT f2bf(float f) {
  __hip_bfloat16 h = __float2bfloat16(f);  // RNE
  return *(ushortT*)&h;
}

__device__ __forceinline__ ucharT f2fp8(float f) {
  unsigned int w = __builtin_amdgcn_cvt_pk_fp8_f32(f, f, 0, false);
  return (ucharT)(w & 0xff);
}

// decode 8 fp8 bytes (two dwords) into f[0..7]
__device__ __forceinline__ void fp8x8_to_f32(unsigned int lo, unsigned int hi,
                                             float* f) {
  float2v p0 = __builtin_amdgcn_cvt_pk_f32_fp8(lo, false);  // bytes 0,1
  float2v p1 = __builtin_amdgcn_cvt_pk_f32_fp8(lo, true);   // bytes 2,3
  float2v p2 = __builtin_amdgcn_cvt_pk_f32_fp8(hi, false);
  float2v p3 = __builtin_amdgcn_cvt_pk_f32_fp8(hi, true);
  f[0] = p0[0]; f[1] = p0[1]; f[2] = p1[0]; f[3] = p1[1];
  f[4] = p2[0]; f[5] = p2[1]; f[6] = p3[0]; f[7] = p3[1];
}

// decode 4 fp8 bytes (one dword) into f[0..3]
__device__ __forceinline__ void fp8x4_to_f32(unsigned int w, float* f) {
  float2v p0 = __builtin_amdgcn_cvt_pk_f32_fp8(w, false);
  float2v p1 = __builtin_amdgcn_cvt_pk_f32_fp8(w, true);
  f[0] = p0[0]; f[1] = p0[1]; f[2] = p1[0]; f[3] = p1[1];
}

// wave-uniform dtype probe: interpret x's first 64 halfwords as bf16 and
// check sanity. Every wave reads the same hot 128B line. Deterministic.
__device__ __forceinline__ bool probe_isbf(const void* xv) {
  const ushortT* xr = (const ushortT*)xv;
  const int lane = threadIdx.x & 63;
  float v = bf2f(xr[lane]);
  bool sane = isfinite(v) && fabsf(v) < 1e4f;
  return __ballot(sane) == ~0ull;
}

// ---------------- W transpose prep: Wt1[nn][k] (128x128), Wt2[nn][k] (64x128) ----------------
__global__ __launch_bounds__(256) void wprep_k(const void* __restrict__ W1v,
                                               const void* __restrict__ W2v,
                                               const void* __restrict__ xv,
                                               ushortT* __restrict__ Wt1,
                                               ushortT* __restrict__ Wt2) {
  const bool isbf = probe_isbf(xv);
  const int i = blockIdx.x * 256 + threadIdx.x;  // 0..24575
  if (i < 16384) {
    int nn = i & 127, k = i >> 7;   // read W1[k][nn] coalesced in nn
    ushortT v = isbf ? ((const ushortT*)W1v)[k * 128 + nn]
                     : f2bf(((const float*)W1v)[k * 128 + nn]);
    Wt1[nn * 128 + k] = v;
  } else if (i < 24576) {
    int j = i - 16384;
    int nn = j & 63, k = j >> 6;    // read W2[k][nn] coalesced in nn
    ushortT v = isbf ? ((const ushortT*)W2v)[k * 64 + nn]
                     : f2bf(((const float*)W2v)[k * 64 + nn]);
    Wt2[nn * 128 + k] = v;
  }
}

// ---------------- bucketed CSR build ----------------
// bucket b = dst >> 8 (256 nodes/bucket), B = ceil(n/256)

__global__ __launch_bounds__(256) void bhist_k(const int* __restrict__ dst, int E, int B,
                                               int* __restrict__ gbc) {
  __shared__ int h[512];
  const int tid = threadIdx.x;
  for (int i = tid; i < B; i += 256) h[i] = 0;
  __syncthreads();
  const int i0 = blockIdx.x * 8192;
  const int iend = min(i0 + 8192, E);
  for (int i = i0 + tid; i < iend; i += 256) atomicAdd(&h[dst[i] >> 8], 1);
  __syncthreads();
  for (int i = tid; i < B; i += 256)
    if (h[i]) atomicAdd(&gbc[i], h[i]);
}

__global__ __launch_bounds__(256) void bscan_k(const int* __restrict__ gbc, int B,
                                               int* __restrict__ bbase,
                                               int* __restrict__ gcur) {
  __shared__ int p[256];
  const int t = threadIdx.x;
  int a = (2 * t < B) ? gbc[2 * t] : 0;
  int b = (2 * t + 1 < B) ? gbc[2 * t + 1] : 0;
  const int sum = a + b;
  p[t] = sum;
  __syncthreads();
  int run = sum;
  for (int off = 1; off < 256; off <<= 1) {
    int v = (t >= off) ? p[t - off] : 0;
    __syncthreads();
    run += v;
    p[t] = run;
    __syncthreads();
  }
  const int excl = run - sum;
  if (2 * t < B) { bbase[2 * t] = excl; gcur[2 * t] = excl; }
  if (2 * t + 1 < B) { bbase[2 * t + 1] = excl + a; gcur[2 * t + 1] = excl + a; }
}

__global__ __launch_bounds__(256) void bin_k(const int* __restrict__ srcv,
                                             const int* __restrict__ dstv, int E, int B,
                                             int* __restrict__ gcur,
                                             int* __restrict__ tmp) {
  __shared__ int hist[512];
  __shared__ int base[512];
  const int tid = threadIdx.x;
  const int i0 = blockIdx.x * 8192;
  const int iend = min(i0 + 8192, E);
  for (int i = tid; i < B; i += 256) hist[i] = 0;
  __syncthreads();
  for (int i = i0 + tid; i < iend; i += 256) atomicAdd(&hist[dstv[i] >> 8], 1);
  __syncthreads();
  for (int i = tid; i < B; i += 256) {
    int h = hist[i];
    base[i] = h ? atomicAdd(&gcur[i], h) : 0;
    hist[i] = 0;  // reuse as local cursor
  }
  __syncthreads();
  for (int i = i0 + tid; i < iend; i += 256) {
    int d = dstv[i];
    int s = srcv[i];
    int b = d >> 8;
    int l = atomicAdd(&hist[b], 1);
    tmp[base[b] + l] = s | ((d & 255) << 17);  // n < 2^17 required (n=100k)
  }
}

// wg per bucket: per-node counts, (row_ptr,count) pack, dis, in-bucket scatter
__global__ __launch_bounds__(256) void csr_k(const int* __restrict__ tmp,
                                             const int* __restrict__ bbase,
                                             const int* __restrict__ gbc, int n,
                                             int2* __restrict__ rpc,
                                             float* __restrict__ dis,
                                             int* __restrict__ col) {
  __shared__ int lhist[256];
  __shared__ int lexcl[256];
  const int b = blockIdx.x;
  const int tid = threadIdx.x;
  const int e0 = bbase[b];
  const int e1 = e0 + gbc[b];
  lhist[tid] = 0;
  __syncthreads();
  for (int i = e0 + tid; i < e1; i += 256) atomicAdd(&lhist[tmp[i] >> 17], 1);
  __syncthreads();
  const int v = lhist[tid];
  int run = v;
  lexcl[tid] = run;
  __syncthreads();
  for (int off = 1; off < 256; off <<= 1) {
    int t = (tid >= off) ? lexcl[tid - off] : 0;
    __syncthreads();
    run += t;
    lexcl[tid] = run;
    __syncthreads();
  }
  const int excl = run - v;
  const int node = (b << 8) + tid;
  if (node < n) {
    rpc[node] = make_int2(e0 + excl, v);
    dis[node] = rsqrtf((float)(v + 1));
  }
  lhist[tid] = 0;
  lexcl[tid] = excl;
  __syncthreads();
  for (int i = e0 + tid; i < e1; i += 256) {
    int p = tmp[i];
    int dloc = p >> 17;
    int s = p & 131071;
    int l = atomicAdd(&lhist[dloc], 1);
    col[e0 + lexcl[dloc] + l] = s;
  }
}

// ---------------- GEMM1 (MFMA): H1'[n+1,128](fp8) = dis * (x @ W1) ----------------
__global__ __launch_bounds__(256) void gemm1_k(const void* __restrict__ xv,
                                               const ushortT* __restrict__ Wt1,
                                               const float* __restrict__ dis,
                                               ucharT* __restrict__ Hb8, int n) {
  __shared__ ushortT sA[64 * 132];
  __shared__ ushortT sW[128 * 132];
  const bool isbf = probe_isbf(xv);
  const int tid = threadIdx.x;
  const int rb = blockIdx.x * 64;
  const int wave = tid >> 6;
  const int lane = tid & 63;
  const int m = lane & 15;
  const int quad = lane >> 4;

  if (isbf) {
    for (int i = tid; i < 2048; i += 256) {
      int r = i >> 5, c4 = (i & 31) * 4;
      ushort4 u = make_ushort4(0, 0, 0, 0);
      if (rb + r < n) u = *(const ushort4*)((const ushortT*)xv + (size_t)(rb + r) * 128 + c4);
      *(ushort4*)&sA[r * 132 + c4] = u;
    }
  } else {
    for (int i = tid; i < 2048; i += 256) {
      int r = i >> 5, c4 = (i & 31) * 4;
      float4 v = make_float4(0.f, 0.f, 0.f, 0.f);
      if (rb + r < n) v = *(const float4*)((const float*)xv + (size_t)(rb + r) * 128 + c4);
      ushort4 u;
      u.x = f2bf(v.x); u.y = f2bf(v.y); u.z = f2bf(v.z); u.w = f2bf(v.w);
      *(ushort4*)&sA[r * 132 + c4] = u;
    }
  }
  // stage Wt1 (coalesced 16B): 128 rows x 128 k = 4096 ushort4 chunks
  for (int i = tid; i < 4096; i += 256) {
    int nn = i >> 5, k4 = (i & 31) * 4;
    *(ushort4*)&sW[nn * 132 + k4] = *(const ushort4*)&Wt1[nn * 128 + k4];
  }
  __syncthreads();

  float4v acc[8];
#pragma unroll
  for (int t = 0; t < 8; ++t) acc[t] = (float4v)(0.f);

  const int arow = wave * 16 + m;
#pragma unroll
  for (int kc = 0; kc < 4; ++kc) {
    short8v af = *(const short8v*)&sA[arow * 132 + kc * 32 + quad * 8];
#pragma unroll
    for (int nb = 0; nb < 8; ++nb) {
      short8v bf = *(const short8v*)&sW[(nb * 16 + m) * 132 + kc * 32 + quad * 8];
      acc[nb] = __builtin_amdgcn_mfma_f32_16x16x32_bf16(af, bf, acc[nb], 0, 0, 0);
    }
  }

  // D: row = rb + wave*16 + quad*4 + r, col = nb*16 + m; store dis*val fp8
  // row n (sentinel) gets zeros. acc==0 for rows >= n (zero-staged x).
#pragma unroll
  for (int r = 0; r < 4; ++r) {
    int grow = rb + wave * 16 + quad * 4 + r;
    if (grow <= n) {
      float sc = (grow < n) ? dis[grow] : 0.f;
#pragma unroll
      for (int nb = 0; nb < 8; ++nb)
        Hb8[(size_t)grow * 128 + nb * 16 + m] =
            (grow < n) ? f2fp8(sc * acc[nb][r]) : (ucharT)0;
    }
  }
}

// ---------------- agg1: A = relu(din*(sum H1'[s] + H1'[i]) + b1) ----------------
// quad-owns-node: each 16-lane quarter owns one node (4 nodes/wave,
// 16/block). 8 ch/lane (8B fp8 gather). Per step each quad processes one
// of its own edges; pad slots cndmask to sentinel row n (zeros). No
// cross-quad reduce; epilogue all-lanes for 4 nodes.
__global__ __launch_bounds__(256) void agg1_k(const ucharT* __restrict__ Hb8,
                                              const int* __restrict__ col,
                                              const int2* __restrict__ rpc,
                                              const float* __restrict__ dis,
                                              const void* __restrict__ b1v,
                                              const void* __restrict__ xv,
                                              ushortT* __restrict__ Ab, int n) {
  const bool isbf = probe_isbf(xv);
  const int tid = threadIdx.x;
  const int lane = tid & 63;
  const int wave = tid >> 6;
  const int quad = lane >> 4;
  const int m = lane & 15;
  const int c8 = m * 8;
  const int node = blockIdx.x * 16 + wave * 4 + quad;
  const bool valid = node < n;
  const int nd = valid ? node : (n - 1);

  const int2 rc = rpc[nd];
  const int start = rc.x;
  const int cnt = valid ? rc.y : 0;
  const float din = dis[nd];

  // hoisted self-row + bias (latency hides under the edge loop)
  const uint2 hsp = *(const uint2*)&Hb8[((unsigned)(valid ? node : n) << 7) + (unsigned)c8];
  float b[8];
  if (isbf) {
    ushort8v bb = *(const ushort8v*)((const ushortT*)b1v + c8);
#pragma unroll
    for (int k = 0; k < 8; ++k) b[k] = bf2f(bb[k]);
  } else {
    const float* bf = (const float*)b1v + c8;
#pragma unroll
    for (int k = 0; k < 8; ++k) b[k] = bf[k];
  }

  // wave-uniform loop bound = max degree among the 4 quads
  int cmax = cnt;
  cmax = max(cmax, __shfl_xor(cmax, 16));
  cmax = max(cmax, __shfl_xor(cmax, 32));
  const int cmaxs = __builtin_amdgcn_readfirstlane(cmax);

  float2v acc[4];
#pragma unroll
  for (int k = 0; k < 4; ++k) acc[k] = (float2v)(0.f);

  for (int e = 0; e < cmaxs; e += 4) {
#pragma unroll
    for (int u = 0; u < 4; ++u) {
      const int ee = e + u;
      int s = col[start + ee];         // col has slack; garbage clamped below
      s = (ee < cnt) ? s : n;          // sentinel: zero row
      const uint2 h = *(const uint2*)&Hb8[((unsigned)s << 7) + (unsigned)c8];
      acc[0] += __builtin_amdgcn_cvt_pk_f32_fp8(h.x, false);
      acc[1] += __builtin_amdgcn_cvt_pk_f32_fp8(h.x, true);
      acc[2] += __builtin_amdgcn_cvt_pk_f32_fp8(h.y, false);
      acc[3] += __builtin_amdgcn_cvt_pk_f32_fp8(h.y, true);
    }
  }

  if (valid) {
    float hs[8];
    fp8x8_to_f32(hsp.x, hsp.y, hs);
    ushort8v o;
#pragma unroll
    for (int k = 0; k < 4; ++k) {
      o[2 * k]     = f2bf(fmaxf(fmaf(din, acc[k][0] + hs[2 * k],     b[2 * k]),     0.f));
      o[2 * k + 1] = f2bf(fmaxf(fmaf(din, acc[k][1] + hs[2 * k + 1], b[2 * k + 1]), 0.f));
    }
    *(ushort8v*)&Ab[(size_t)node * 128 + c8] = o;
  }
}

// ---------------- GEMM2 (MFMA): H2'[n+1,64](fp8) = dis * (A @ W2) ----------------
__global__ __launch_bounds__(256) void gemm2_k(const ushortT* __restrict__ Ab,
                                               const ushortT* __restrict__ Wt2,
                                               const float* __restrict__ dis,
                                               ucharT* __restrict__ H2b8, int n) {
  __shared__ ushortT sA[64 * 132];
  __shared__ ushortT sW[64 * 132];
  const int tid = threadIdx.x;
  const int rb = blockIdx.x * 64;
  const int wave = tid >> 6;
  const int lane = tid & 63;
  const int m = lane & 15;
  const int quad = lane >> 4;

  for (int i = tid; i < 2048; i += 256) {
    int r = i >> 5, c4 = (i & 31) * 4;
    ushort4 u = make_ushort4(0, 0, 0, 0);
    if (rb + r < n) u = *(const ushort4*)&Ab[(size_t)(rb + r) * 128 + c4];
    *(ushort4*)&sA[r * 132 + c4] = u;
  }
  // stage Wt2 (coalesced 16B): 64 rows x 128 k = 2048 ushort4 chunks
  for (int i = tid; i < 2048; i += 256) {
    int nn = i >> 5, k4 = (i & 31) * 4;
    *(ushort4*)&sW[nn * 132 + k4] = *(const ushort4*)&Wt2[nn * 128 + k4];
  }
  __syncthreads();

  float4v acc[4];
#pragma unroll
  for (int t = 0; t < 4; ++t) acc[t] = (float4v)(0.f);

  const int arow = wave * 16 + m;
#pragma unroll
  for (int kc = 0; kc < 4; ++kc) {
    short8v af = *(const short8v*)&sA[arow * 132 + kc * 32 + quad * 8];
#pragma unroll
    for (int nb = 0; nb < 4; ++nb) {
      short8v bf = *(const short8v*)&sW[(nb * 16 + m) * 132 + kc * 32 + quad * 8];
      acc[nb] = __builtin_amdgcn_mfma_f32_16x16x32_bf16(af, bf, acc[nb], 0, 0, 0);
    }
  }

#pragma unroll
  for (int r = 0; r < 4; ++r) {
    int grow = rb + wave * 16 + quad * 4 + r;
    if (grow <= n) {
      float sc = (grow < n) ? dis[grow] : 0.f;
#pragma unroll
      for (int nb = 0; nb < 4; ++nb)
        H2b8[(size_t)grow * 64 + nb * 16 + m] =
            (grow < n) ? f2fp8(sc * acc[nb][r]) : (ucharT)0;
    }
  }
}

// ---------------- agg2 + log_softmax -> out ----------------
// quad-owns-node; 4 ch/lane (4B fp8 gather); per-quad softmax (shfl_xor
// 1..8 stays inside the 16-lane group); all-lanes output store.
__global__ __launch_bounds__(256) void agg2_k(const ucharT* __restrict__ H2b8,
                                              const int* __restrict__ col,
                                              const int2* __restrict__ rpc,
                                              const float* __restrict__ dis,
                                              const void* __restrict__ b2v,
                                              const void* __restrict__ xv,
                                              void* __restrict__ outv, int n) {
  const bool isbf = probe_isbf(xv);
  const int tid = threadIdx.x;
  const int lane = tid & 63;
  const int wave = tid >> 6;
  const int quad = lane >> 4;
  const int m = lane & 15;
  const int c4 = m * 4;
  const int node = blockIdx.x * 16 + wave * 4 + quad;
  const bool valid = node < n;
  const int nd = valid ? node : (n - 1);

  const int2 rc = rpc[nd];
  const int start = rc.x;
  const int cnt = valid ? rc.y : 0;
  const float din = dis[nd];

  const unsigned int hsp =
      *(const unsigned int*)&H2b8[((unsigned)(valid ? node : n) << 6) + (unsigned)c4];
  float b[4];
  if (isbf) {
    ushort4 bb = *(const ushort4*)((const ushortT*)b2v + c4);
    b[0] = bf2f(bb.x); b[1] = bf2f(bb.y); b[2] = bf2f(bb.z); b[3] = bf2f(bb.w);
  } else {
    const float* bf = (const float*)b2v + c4;
#pragma unroll
    for (int k = 0; k < 4; ++k) b[k] = bf[k];
  }

  int cmax = cnt;
  cmax = max(cmax, __shfl_xor(cmax, 16));
  cmax = max(cmax, __shfl_xor(cmax, 32));
  const int cmaxs = __builtin_amdgcn_readfirstlane(cmax);

  float2v acc[2];
  acc[0] = (float2v)(0.f);
  acc[1] = (float2v)(0.f);

  for (int e = 0; e < cmaxs; e += 4) {
#pragma unroll
    for (int u = 0; u < 4; ++u) {
      const int ee = e + u;
      int s = col[start + ee];
      s = (ee < cnt) ? s : n;          // sentinel: zero row
      const unsigned int h = *(const unsigned int*)&H2b8[((unsigned)s << 6) + (unsigned)c4];
      acc[0] += __builtin_amdgcn_cvt_pk_f32_fp8(h, false);
      acc[1] += __builtin_amdgcn_cvt_pk_f32_fp8(h, true);
    }
  }

  float hs[4];
  fp8x4_to_f32(hsp, hs);
  float v[4];
  v[0] = fmaf(din, acc[0][0] + hs[0], b[0]);
  v[1] = fmaf(din, acc[0][1] + hs[1], b[1]);
  v[2] = fmaf(din, acc[1][0] + hs[2], b[2]);
  v[3] = fmaf(din, acc[1][1] + hs[3], b[3]);

  // log_softmax over 64 channels: local 4 + 16-lane group reduce (in-quad)
  float mx = fmaxf(fmaxf(v[0], v[1]), fmaxf(v[2], v[3]));
  for (int off = 1; off < 16; off <<= 1) mx = fmaxf(mx, __shfl_xor(mx, off));
  float ssum = __expf(v[0] - mx) + __expf(v[1] - mx) + __expf(v[2] - mx) + __expf(v[3] - mx);
  for (int off = 1; off < 16; off <<= 1) ssum += __shfl_xor(ssum, off);
  const float lse = mx + __logf(ssum);

  if (valid) {
    if (isbf) {
      ushort4 o;
      o.x = f2bf(v[0] - lse); o.y = f2bf(v[1] - lse);
      o.z = f2bf(v[2] - lse); o.w = f2bf(v[3] - lse);
      *(ushort4*)((__hip_bfloat16*)outv + (size_t)node * 64 + c4) = o;
    } else {
      float4 o = make_float4(v[0] - lse, v[1] - lse, v[2] - lse, v[3] - lse);
      *(float4*)((float*)outv + (size_t)node * 64 + c4) = o;
    }
  }
}

// ---------------- launch ----------------

extern "C" void kernel_launch(void* const* d_in, const int* in_sizes, int n_in,
                              void* d_out, int out_size, void* d_ws, size_t ws_size,
                              hipStream_t stream) {
  const void* x  = d_in[0];
  const int*  ei = (const int*)d_in[1];
  const void* W1 = d_in[2];
  const void* b1 = d_in[3];
  const void* W2 = d_in[4];
  const void* b2 = d_in[5];

  const int n = in_sizes[0] / 128;
  const int E = in_sizes[1] / 2;
  const int B = (n + 255) >> 8;  // buckets of 256 nodes
  const int* srcv = ei;      // edge_index[0]
  const int* dstv = ei + E;  // edge_index[1]

  // workspace layout (~60 MB), 256B-aligned sections
  char* p = (char*)d_ws;
  auto alloc = [&](size_t bytes) {
    char* q = p;
    p += (bytes + 255) & ~(size_t)255;
    return q;
  };
  ucharT* Hb8 = (ucharT*)alloc((size_t)(n + 1) * 128);      // H1' fp8, +sentinel row
  ucharT* H2b8 = (ucharT*)alloc((size_t)(n + 1) * 64);      // H2' fp8, +sentinel row
  ushortT* Ab = (ushortT*)alloc((size_t)n * 128 * 2);       // A bf16
  float* dis = (float*)alloc((size_t)n * 4);
  int2* rpc = (int2*)alloc((size_t)n * 8);                  // (row_ptr, count)
  int* gbc = (int*)alloc(512 * 4);
  int* bbase = (int*)alloc(512 * 4);
  int* gcur = (int*)alloc(512 * 4);
  ushortT* Wt1 = (ushortT*)alloc(16384 * 2);
  ushortT* Wt2 = (ushortT*)alloc(8192 * 2);
  int* tmp = (int*)alloc((size_t)E * 4);
  int* col = (int*)alloc(((size_t)E + 4096) * 4);  // slack for pad-slot reads

  (void)hipMemsetAsync(gbc, 0, 512 * sizeof(int), stream);

  const int gChunks = (E + 8191) / 8192;

  wprep_k<<<96, 256, 0, stream>>>(W1, W2, x, Wt1, Wt2);
  bhist_k<<<gChunks, 256, 0, stream>>>(dstv, E, B, gbc);
  bscan_k<<<1, 256, 0, stream>>>(gbc, B, bbase, gcur);
  bin_k<<<gChunks, 256, 0, stream>>>(srcv, dstv, E, B, gcur, tmp);
  csr_k<<<B, 256, 0, stream>>>(tmp, bbase, gbc, n, rpc, dis, col);

  gemm1_k<<<(n + 63) / 64, 256, 0, stream>>>(x, Wt1, dis, Hb8, n);
  agg1_k<<<(n + 15) / 16, 256, 0, stream>>>(Hb8, col, rpc, dis, b1, x, Ab, n);
  gemm2_k<<<(n + 63) / 64, 256, 0, stream>>>(Ab, Wt2, dis, H2b8, n);
  agg2_k<<<(n + 15) / 16, 256, 0, stream>>>(H2b8, col, rpc, dis, b2, x, d_out, n);
}

// Round 3
// 238.436 us; speedup vs baseline: 1.1944x; 1.0771x over previous
//
#include <hip/hip_runtime.h>
#include <hip/hip_bf16.h>

// GCN 2-layer forward on MI355X.
// Round-12 changes (gemm1 40.9us at 2.8% MfmaUtil / 12% HBM / 21% occ —
// latency-bound: 1563 tiny blocks each re-staging W(33KB)+x(17KB) into LDS
// with a full barrier before 32 MFMAs):
//  - gemm1/gemm2 restructured: 512-thread blocks, 128 rows each. W staged
//    into LDS ONCE per block (single barrier), x/A fragments loaded
//    DIRECTLY from global in MFMA layout (lane(m,quad) reads 16B at
//    row m, k=kc*32+quad*8 — wave covers 16 rows x 64B sectors per
//    instruction, DRAM-perfect). No sA, no per-tile barrier; waves run
//    independently after the W stage.
//  - grid covers n+1 rows so the sentinel row is still zeroed when n is a
//    multiple of the row tile.
// Quad-owns-node aggs (r11), direct col loads + sentinel (r10), pre-scaled
// fp8 features (r9), bucketed CSR (r5) kept.

typedef unsigned short ushortT;
typedef unsigned char ucharT;
typedef __attribute__((ext_vector_type(8))) short short8v;        // 8 bf16 (4 VGPR)
typedef __attribute__((ext_vector_type(4))) float float4v;        // MFMA C/D
typedef __attribute__((ext_vector_type(2))) float float2v;
typedef __attribute__((ext_vector_type(8))) unsigned short ushort8v;

__device__ __forceinline__ float bf2f(ushortT u) {
  union { unsigned int i; float f; } x;
  x.i = ((unsigned int)u) << 16;
  return x.f;
}

__device__ __forceinline__ ushortT f2bf(float f) {
  __hip_bfloat16 h = __float2bfloat16(f);  // RNE
  return *(ushortT*)&h;
}

__device__ __forceinline__ ucharT f2fp8(float f) {
  unsigned int w = __builtin_amdgcn_cvt_pk_fp8_f32(f, f, 0, false);
  return (ucharT)(w & 0xff);
}

// decode 8 fp8 bytes (two dwords) into f[0..7]
__device__ __forceinline__ void fp8x8_to_f32(unsigned int lo, unsigned int hi,
                                             float* f) {
  float2v p0 = __builtin_amdgcn_cvt_pk_f32_fp8(lo, false);  // bytes 0,1
  float2v p1 = __builtin_amdgcn_cvt_pk_f32_fp8(lo, true);   // bytes 2,3
  float2v p2 = __builtin_amdgcn_cvt_pk_f32_fp8(hi, false);
  float2v p3 = __builtin_amdgcn_cvt_pk_f32_fp8(hi, true);
  f[0] = p0[0]; f[1] = p0[1]; f[2] = p1[0]; f[3] = p1[1];
  f[4] = p2[0]; f[5] = p2[1]; f[6] = p3[0]; f[7] = p3[1];
}

// decode 4 fp8 bytes (one dword) into f[0..3]
__device__ __forceinline__ void fp8x4_to_f32(unsigned int w, float* f) {
  float2v p0 = __builtin_amdgcn_cvt_pk_f32_fp8(w, false);
  float2v p1 = __builtin_amdgcn_cvt_pk_f32_fp8(w, true);
  f[0] = p0[0]; f[1] = p0[1]; f[2] = p1[0]; f[3] = p1[1];
}

// wave-uniform dtype probe: interpret x's first 64 halfwords as bf16 and
// check sanity. Every wave reads the same hot 128B line. Deterministic.
__device__ __forceinline__ bool probe_isbf(const void* xv) {
  const ushortT* xr = (const ushortT*)xv;
  const int lane = threadIdx.x & 63;
  float v = bf2f(xr[lane]);
  bool sane = isfinite(v) && fabsf(v) < 1e4f;
  return __ballot(sane) == ~0ull;
}

// ---------------- W transpose prep: Wt1[nn][k] (128x128), Wt2[nn][k] (64x128) ----------------
__global__ __launch_bounds__(256) void wprep_k(const void* __restrict__ W1v,
                                               const void* __restrict__ W2v,
                                               const void* __restrict__ xv,
                                               ushortT* __restrict__ Wt1,
                                               ushortT* __restrict__ Wt2) {
  const bool isbf = probe_isbf(xv);
  const int i = blockIdx.x * 256 + threadIdx.x;  // 0..24575
  if (i < 16384) {
    int nn = i & 127, k = i >> 7;   // read W1[k][nn] coalesced in nn
    ushortT v = isbf ? ((const ushortT*)W1v)[k * 128 + nn]
                     : f2bf(((const float*)W1v)[k * 128 + nn]);
    Wt1[nn * 128 + k] = v;
  } else if (i < 24576) {
    int j = i - 16384;
    int nn = j & 63, k = j >> 6;    // read W2[k][nn] coalesced in nn
    ushortT v = isbf ? ((const ushortT*)W2v)[k * 64 + nn]
                     : f2bf(((const float*)W2v)[k * 64 + nn]);
    Wt2[nn * 128 + k] = v;
  }
}

// ---------------- bucketed CSR build ----------------
// bucket b = dst >> 8 (256 nodes/bucket), B = ceil(n/256)

__global__ __launch_bounds__(256) void bhist_k(const int* __restrict__ dst, int E, int B,
                                               int* __restrict__ gbc) {
  __shared__ int h[512];
  const int tid = threadIdx.x;
  for (int i = tid; i < B; i += 256) h[i] = 0;
  __syncthreads();
  const int i0 = blockIdx.x * 8192;
  const int iend = min(i0 + 8192, E);
  for (int i = i0 + tid; i < iend; i += 256) atomicAdd(&h[dst[i] >> 8], 1);
  __syncthreads();
  for (int i = tid; i < B; i += 256)
    if (h[i]) atomicAdd(&gbc[i], h[i]);
}

__global__ __launch_bounds__(256) void bscan_k(const int* __restrict__ gbc, int B,
                                               int* __restrict__ bbase,
                                               int* __restrict__ gcur) {
  __shared__ int p[256];
  const int t = threadIdx.x;
  int a = (2 * t < B) ? gbc[2 * t] : 0;
  int b = (2 * t + 1 < B) ? gbc[2 * t + 1] : 0;
  const int sum = a + b;
  p[t] = sum;
  __syncthreads();
  int run = sum;
  for (int off = 1; off < 256; off <<= 1) {
    int v = (t >= off) ? p[t - off] : 0;
    __syncthreads();
    run += v;
    p[t] = run;
    __syncthreads();
  }
  const int excl = run - sum;
  if (2 * t < B) { bbase[2 * t] = excl; gcur[2 * t] = excl; }
  if (2 * t + 1 < B) { bbase[2 * t + 1] = excl + a; gcur[2 * t + 1] = excl + a; }
}

__global__ __launch_bounds__(256) void bin_k(const int* __restrict__ srcv,
                                             const int* __restrict__ dstv, int E, int B,
                                             int* __restrict__ gcur,
                                             int* __restrict__ tmp) {
  __shared__ int hist[512];
  __shared__ int base[512];
  const int tid = threadIdx.x;
  const int i0 = blockIdx.x * 8192;
  const int iend = min(i0 + 8192, E);
  for (int i = tid; i < B; i += 256) hist[i] = 0;
  __syncthreads();
  for (int i = i0 + tid; i < iend; i += 256) atomicAdd(&hist[dstv[i] >> 8], 1);
  __syncthreads();
  for (int i = tid; i < B; i += 256) {
    int h = hist[i];
    base[i] = h ? atomicAdd(&gcur[i], h) : 0;
    hist[i] = 0;  // reuse as local cursor
  }
  __syncthreads();
  for (int i = i0 + tid; i < iend; i += 256) {
    int d = dstv[i];
    int s = srcv[i];
    int b = d >> 8;
    int l = atomicAdd(&hist[b], 1);
    tmp[base[b] + l] = s | ((d & 255) << 17);  // n < 2^17 required (n=100k)
  }
}

// wg per bucket: per-node counts, (row_ptr,count) pack, dis, in-bucket scatter
__global__ __launch_bounds__(256) void csr_k(const int* __restrict__ tmp,
                                             const int* __restrict__ bbase,
                                             const int* __restrict__ gbc, int n,
                                             int2* __restrict__ rpc,
                                             float* __restrict__ dis,
                                             int* __restrict__ col) {
  __shared__ int lhist[256];
  __shared__ int lexcl[256];
  const int b = blockIdx.x;
  const int tid = threadIdx.x;
  const int e0 = bbase[b];
  const int e1 = e0 + gbc[b];
  lhist[tid] = 0;
  __syncthreads();
  for (int i = e0 + tid; i < e1; i += 256) atomicAdd(&lhist[tmp[i] >> 17], 1);
  __syncthreads();
  const int v = lhist[tid];
  int run = v;
  lexcl[tid] = run;
  __syncthreads();
  for (int off = 1; off < 256; off <<= 1) {
    int t = (tid >= off) ? lexcl[tid - off] : 0;
    __syncthreads();
    run += t;
    lexcl[tid] = run;
    __syncthreads();
  }
  const int excl = run - v;
  const int node = (b << 8) + tid;
  if (node < n) {
    rpc[node] = make_int2(e0 + excl, v);
    dis[node] = rsqrtf((float)(v + 1));
  }
  lhist[tid] = 0;
  lexcl[tid] = excl;
  __syncthreads();
  for (int i = e0 + tid; i < e1; i += 256) {
    int p = tmp[i];
    int dloc = p >> 17;
    int s = p & 131071;
    int l = atomicAdd(&lhist[dloc], 1);
    col[e0 + lexcl[dloc] + l] = s;
  }
}

// ---------------- GEMM1 (MFMA): H1'[n+1,128](fp8) = dis * (x @ W1) ----------------
// 512 threads, 128 rows/block. W staged once in LDS (one barrier); A
// fragments loaded directly from global in MFMA layout.
__global__ __launch_bounds__(512) void gemm1_k(const void* __restrict__ xv,
                                               const ushortT* __restrict__ Wt1,
                                               const float* __restrict__ dis,
                                               ucharT* __restrict__ Hb8, int n) {
  __shared__ ushortT sW[128 * 132];
  const bool isbf = probe_isbf(xv);
  const int tid = threadIdx.x;
  // stage Wt1 (coalesced 16B): 128 rows x 128 k = 4096 ushort4 chunks
  for (int i = tid; i < 4096; i += 512) {
    int nn = i >> 5, k4 = (i & 31) * 4;
    *(ushort4*)&sW[nn * 132 + k4] = *(const ushort4*)&Wt1[nn * 128 + k4];
  }
  __syncthreads();

  const int wave = tid >> 6;
  const int lane = tid & 63;
  const int m = lane & 15;
  const int quad = lane >> 4;
  const int row = blockIdx.x * 128 + wave * 16 + m;
  const int rowc = min(row, n - 1);  // clamp keeps loads in-bounds; OOB rows masked at store

  float4v acc[8];
#pragma unroll
  for (int t = 0; t < 8; ++t) acc[t] = (float4v)(0.f);

  if (isbf) {
    const ushortT* xp = (const ushortT*)xv + (size_t)rowc * 128 + quad * 8;
#pragma unroll
    for (int kc = 0; kc < 4; ++kc) {
      short8v af = *(const short8v*)(xp + kc * 32);
#pragma unroll
      for (int nb = 0; nb < 8; ++nb) {
        short8v bf = *(const short8v*)&sW[(nb * 16 + m) * 132 + kc * 32 + quad * 8];
        acc[nb] = __builtin_amdgcn_mfma_f32_16x16x32_bf16(af, bf, acc[nb], 0, 0, 0);
      }
    }
  } else {
    const float* xp = (const float*)xv + (size_t)rowc * 128 + quad * 8;
#pragma unroll
    for (int kc = 0; kc < 4; ++kc) {
      float4 lo = *(const float4*)(xp + kc * 32);
      float4 hi = *(const float4*)(xp + kc * 32 + 4);
      short8v af;
      af[0] = (short)f2bf(lo.x); af[1] = (short)f2bf(lo.y);
      af[2] = (short)f2bf(lo.z); af[3] = (short)f2bf(lo.w);
      af[4] = (short)f2bf(hi.x); af[5] = (short)f2bf(hi.y);
      af[6] = (short)f2bf(hi.z); af[7] = (short)f2bf(hi.w);
#pragma unroll
      for (int nb = 0; nb < 8; ++nb) {
        short8v bf = *(const short8v*)&sW[(nb * 16 + m) * 132 + kc * 32 + quad * 8];
        acc[nb] = __builtin_amdgcn_mfma_f32_16x16x32_bf16(af, bf, acc[nb], 0, 0, 0);
      }
    }
  }

  // D: row = blk*128 + wave*16 + quad*4 + r, col = nb*16 + m; store dis*val fp8
  // row n (sentinel) gets explicit zeros.
#pragma unroll
  for (int r = 0; r < 4; ++r) {
    int grow = blockIdx.x * 128 + wave * 16 + quad * 4 + r;
    if (grow <= n) {
      float sc = (grow < n) ? dis[grow] : 0.f;
#pragma unroll
      for (int nb = 0; nb < 8; ++nb)
        Hb8[(size_t)grow * 128 + nb * 16 + m] =
            (grow < n) ? f2fp8(sc * acc[nb][r]) : (ucharT)0;
    }
  }
}

// ---------------- agg1: A = relu(din*(sum H1'[s] + H1'[i]) + b1) ----------------
// quad-owns-node: each 16-lane quarter owns one node (4 nodes/wave,
// 16/block). 8 ch/lane (8B fp8 gather). Per step each quad processes one
// of its own edges; pad slots cndmask to sentinel row n (zeros). No
// cross-quad reduce; epilogue all-lanes for 4 nodes.
__global__ __launch_bounds__(256) void agg1_k(const ucharT* __restrict__ Hb8,
                                              const int* __restrict__ col,
                                              const int2* __restrict__ rpc,
                                              const float* __restrict__ dis,
                                              const void* __restrict__ b1v,
                                              const void* __restrict__ xv,
                                              ushortT* __restrict__ Ab, int n) {
  const bool isbf = probe_isbf(xv);
  const int tid = threadIdx.x;
  const int lane = tid & 63;
  const int wave = tid >> 6;
  const int quad = lane >> 4;
  const int m = lane & 15;
  const int c8 = m * 8;
  const int node = blockIdx.x * 16 + wave * 4 + quad;
  const bool valid = node < n;
  const int nd = valid ? node : (n - 1);

  const int2 rc = rpc[nd];
  const int start = rc.x;
  const int cnt = valid ? rc.y : 0;
  const float din = dis[nd];

  // hoisted self-row + bias (latency hides under the edge loop)
  const uint2 hsp = *(const uint2*)&Hb8[((unsigned)(valid ? node : n) << 7) + (unsigned)c8];
  float b[8];
  if (isbf) {
    ushort8v bb = *(const ushort8v*)((const ushortT*)b1v + c8);
#pragma unroll
    for (int k = 0; k < 8; ++k) b[k] = bf2f(bb[k]);
  } else {
    const float* bf = (const float*)b1v + c8;
#pragma unroll
    for (int k = 0; k < 8; ++k) b[k] = bf[k];
  }

  // wave-uniform loop bound = max degree among the 4 quads
  int cmax = cnt;
  cmax = max(cmax, __shfl_xor(cmax, 16));
  cmax = max(cmax, __shfl_xor(cmax, 32));
  const int cmaxs = __builtin_amdgcn_readfirstlane(cmax);

  float2v acc[4];
#pragma unroll
  for (int k = 0; k < 4; ++k) acc[k] = (float2v)(0.f);

  for (int e = 0; e < cmaxs; e += 4) {
#pragma unroll
    for (int u = 0; u < 4; ++u) {
      const int ee = e + u;
      int s = col[start + ee];         // col has slack; garbage clamped below
      s = (ee < cnt) ? s : n;          // sentinel: zero row
      const uint2 h = *(const uint2*)&Hb8[((unsigned)s << 7) + (unsigned)c8];
      acc[0] += __builtin_amdgcn_cvt_pk_f32_fp8(h.x, false);
      acc[1] += __builtin_amdgcn_cvt_pk_f32_fp8(h.x, true);
      acc[2] += __builtin_amdgcn_cvt_pk_f32_fp8(h.y, false);
      acc[3] += __builtin_amdgcn_cvt_pk_f32_fp8(h.y, true);
    }
  }

  if (valid) {
    float hs[8];
    fp8x8_to_f32(hsp.x, hsp.y, hs);
    ushort8v o;
#pragma unroll
    for (int k = 0; k < 4; ++k) {
      o[2 * k]     = f2bf(fmaxf(fmaf(din, acc[k][0] + hs[2 * k],     b[2 * k]),     0.f));
      o[2 * k + 1] = f2bf(fmaxf(fmaf(din, acc[k][1] + hs[2 * k + 1], b[2 * k + 1]), 0.f));
    }
    *(ushort8v*)&Ab[(size_t)node * 128 + c8] = o;
  }
}

// ---------------- GEMM2 (MFMA): H2'[n+1,64](fp8) = dis * (A @ W2) ----------------
// 512 threads, 128 rows/block; W staged once; A fragments direct from global.
__global__ __launch_bounds__(512) void gemm2_k(const ushortT* __restrict__ Ab,
                                               const ushortT* __restrict__ Wt2,
                                               const float* __restrict__ dis,
                                               ucharT* __restrict__ H2b8, int n) {
  __shared__ ushortT sW[64 * 132];
  const int tid = threadIdx.x;
  // stage Wt2 (coalesced 16B): 64 rows x 128 k = 2048 ushort4 chunks
  for (int i = tid; i < 2048; i += 512) {
    int nn = i >> 5, k4 = (i & 31) * 4;
    *(ushort4*)&sW[nn * 132 + k4] = *(const ushort4*)&Wt2[nn * 128 + k4];
  }
  __syncthreads();

  const int wave = tid >> 6;
  const int lane = tid & 63;
  const int m = lane & 15;
  const int quad = lane >> 4;
  const int row = blockIdx.x * 128 + wave * 16 + m;
  const int rowc = min(row, n - 1);

  float4v acc[4];
#pragma unroll
  for (int t = 0; t < 4; ++t) acc[t] = (float4v)(0.f);

  const ushortT* ap = Ab + (size_t)rowc * 128 + quad * 8;
#pragma unroll
  for (int kc = 0; kc < 4; ++kc) {
    short8v af = *(const short8v*)(ap + kc * 32);
#pragma unroll
    for (int nb = 0; nb < 4; ++nb) {
      short8v bf = *(const short8v*)&sW[(nb * 16 + m) * 132 + kc * 32 + quad * 8];
      acc[nb] = __builtin_amdgcn_mfma_f32_16x16x32_bf16(af, bf, acc[nb], 0, 0, 0);
    }
  }

#pragma unroll
  for (int r = 0; r < 4; ++r) {
    int grow = blockIdx.x * 128 + wave * 16 + quad * 4 + r;
    if (grow <= n) {
      float sc = (grow < n) ? dis[grow] : 0.f;
#pragma unroll
      for (int nb = 0; nb < 4; ++nb)
        H2b8[(size_t)grow * 64 + nb * 16 + m] =
            (grow < n) ? f2fp8(sc * acc[nb][r]) : (ucharT)0;
    }
  }
}

// ---------------- agg2 + log_softmax -> out ----------------
// quad-owns-node; 4 ch/lane (4B fp8 gather); per-quad softmax (shfl_xor
// 1..8 stays inside the 16-lane group); all-lanes output store.
__global__ __launch_bounds__(256) void agg2_k(const ucharT* __restrict__ H2b8,
                                              const int* __restrict__ col,
                                              const int2* __restrict__ rpc,
                                              const float* __restrict__ dis,
                                              const void* __restrict__ b2v,
                                              const void* __restrict__ xv,
                                              void* __restrict__ outv, int n) {
  const bool isbf = probe_isbf(xv);
  const int tid = threadIdx.x;
  const int lane = tid & 63;
  const int wave = tid >> 6;
  const int quad = lane >> 4;
  const int m = lane & 15;
  const int c4 = m * 4;
  const int node = blockIdx.x * 16 + wave * 4 + quad;
  const bool valid = node < n;
  const int nd = valid ? node : (n - 1);

  const int2 rc = rpc[nd];
  const int start = rc.x;
  const int cnt = valid ? rc.y : 0;
  const float din = dis[nd];

  const unsigned int hsp =
      *(const unsigned int*)&H2b8[((unsigned)(valid ? node : n) << 6) + (unsigned)c4];
  float b[4];
  if (isbf) {
    ushort4 bb = *(const ushort4*)((const ushortT*)b2v + c4);
    b[0] = bf2f(bb.x); b[1] = bf2f(bb.y); b[2] = bf2f(bb.z); b[3] = bf2f(bb.w);
  } else {
    const float* bf = (const float*)b2v + c4;
#pragma unroll
    for (int k = 0; k < 4; ++k) b[k] = bf[k];
  }

  int cmax = cnt;
  cmax = max(cmax, __shfl_xor(cmax, 16));
  cmax = max(cmax, __shfl_xor(cmax, 32));
  const int cmaxs = __builtin_amdgcn_readfirstlane(cmax);

  float2v acc[2];
  acc[0] = (float2v)(0.f);
  acc[1] = (float2v)(0.f);

  for (int e = 0; e < cmaxs; e += 4) {
#pragma unroll
    for (int u = 0; u < 4; ++u) {
      const int ee = e + u;
      int s = col[start + ee];
      s = (ee < cnt) ? s : n;          // sentinel: zero row
      const unsigned int h = *(const unsigned int*)&H2b8[((unsigned)s << 6) + (unsigned)c4];
      acc[0] += __builtin_amdgcn_cvt_pk_f32_fp8(h, false);
      acc[1] += __builtin_amdgcn_cvt_pk_f32_fp8(h, true);
    }
  }

  float hs[4];
  fp8x4_to_f32(hsp, hs);
  float v[4];
  v[0] = fmaf(din, acc[0][0] + hs[0], b[0]);
  v[1] = fmaf(din, acc[0][1] + hs[1], b[1]);
  v[2] = fmaf(din, acc[1][0] + hs[2], b[2]);
  v[3] = fmaf(din, acc[1][1] + hs[3], b[3]);

  // log_softmax over 64 channels: local 4 + 16-lane group reduce (in-quad)
  float mx = fmaxf(fmaxf(v[0], v[1]), fmaxf(v[2], v[3]));
  for (int off = 1; off < 16; off <<= 1) mx = fmaxf(mx, __shfl_xor(mx, off));
  float ssum = __expf(v[0] - mx) + __expf(v[1] - mx) + __expf(v[2] - mx) + __expf(v[3] - mx);
  for (int off = 1; off < 16; off <<= 1) ssum += __shfl_xor(ssum, off);
  const float lse = mx + __logf(ssum);

  if (valid) {
    if (isbf) {
      ushort4 o;
      o.x = f2bf(v[0] - lse); o.y = f2bf(v[1] - lse);
      o.z = f2bf(v[2] - lse); o.w = f2bf(v[3] - lse);
      *(ushort4*)((__hip_bfloat16*)outv + (size_t)node * 64 + c4) = o;
    } else {
      float4 o = make_float4(v[0] - lse, v[1] - lse, v[2] - lse, v[3] - lse);
      *(float4*)((float*)outv + (size_t)node * 64 + c4) = o;
    }
  }
}

// ---------------- launch ----------------

extern "C" void kernel_launch(void* const* d_in, const int* in_sizes, int n_in,
                              void* d_out, int out_size, void* d_ws, size_t ws_size,
                              hipStream_t stream) {
  const void* x  = d_in[0];
  const int*  ei = (const int*)d_in[1];
  const void* W1 = d_in[2];
  const void* b1 = d_in[3];
  const void* W2 = d_in[4];
  const void* b2 = d_in[5];

  const int n = in_sizes[0] / 128;
  const int E = in_sizes[1] / 2;
  const int B = (n + 255) >> 8;  // buckets of 256 nodes
  const int* srcv = ei;      // edge_index[0]
  const int* dstv = ei + E;  // edge_index[1]

  // workspace layout (~60 MB), 256B-aligned sections
  char* p = (char*)d_ws;
  auto alloc = [&](size_t bytes) {
    char* q = p;
    p += (bytes + 255) & ~(size_t)255;
    return q;
  };
  ucharT* Hb8 = (ucharT*)alloc((size_t)(n + 1) * 128);      // H1' fp8, +sentinel row
  ucharT* H2b8 = (ucharT*)alloc((size_t)(n + 1) * 64);      // H2' fp8, +sentinel row
  ushortT* Ab = (ushortT*)alloc((size_t)n * 128 * 2);       // A bf16
  float* dis = (float*)alloc((size_t)n * 4);
  int2* rpc = (int2*)alloc((size_t)n * 8);                  // (row_ptr, count)
  int* gbc = (int*)alloc(512 * 4);
  int* bbase = (int*)alloc(512 * 4);
  int* gcur = (int*)alloc(512 * 4);
  ushortT* Wt1 = (ushortT*)alloc(16384 * 2);
  ushortT* Wt2 = (ushortT*)alloc(8192 * 2);
  int* tmp = (int*)alloc((size_t)E * 4);
  int* col = (int*)alloc(((size_t)E + 4096) * 4);  // slack for pad-slot reads

  (void)hipMemsetAsync(gbc, 0, 512 * sizeof(int), stream);

  const int gChunks = (E + 8191) / 8192;

  wprep_k<<<96, 256, 0, stream>>>(W1, W2, x, Wt1, Wt2);
  bhist_k<<<gChunks, 256, 0, stream>>>(dstv, E, B, gbc);
  bscan_k<<<1, 256, 0, stream>>>(gbc, B, bbase, gcur);
  bin_k<<<gChunks, 256, 0, stream>>>(srcv, dstv, E, B, gcur, tmp);
  csr_k<<<B, 256, 0, stream>>>(tmp, bbase, gbc, n, rpc, dis, col);

  // grids cover n+1 rows so the sentinel row is written even when n%128==0
  gemm1_k<<<(n + 128) / 128, 512, 0, stream>>>(x, Wt1, dis, Hb8, n);
  agg1_k<<<(n + 15) / 16, 256, 0, stream>>>(Hb8, col, rpc, dis, b1, x, Ab, n);
  gemm2_k<<<(n + 128) / 128, 512, 0, stream>>>(Ab, Wt2, dis, H2b8, n);
  agg2_k<<<(n + 15) / 16, 256, 0, stream>>>(H2b8, col, rpc, dis, b2, x, d_out, n);
}